// Round 5
// baseline (146.294 us; speedup 1.0000x reference)
//
#include <hip/hip_runtime.h>
#include <stdint.h>

// pooled[b,p] = sum_{n in seg b} max_e ( proxy[p,e,:] . x[n,:] );  out = L2-normalized rows.
// P=128, E=32, D=64, B=1024 segments. Ragged handled via zeroed-B masking.
//
// R4 remap: MFMA rows = 32 p's (p-group per wave), e is a register-resident
// running-max loop — NO shuffles / LDS / cross-lane ops in the inner loop.
//   per e: 16 MFMAs (4 n-tiles x K=64, zero-C start) + 64 v_max. Reductions
//   (tile-sum, col-sum, L2-normalize) run once per pass via LDS.
// A (proxy) is fragment-major bf16: frag(g,e,kk) = contiguous 1KB, lane*16B
// slots -> perfectly coalesced; dbuf prefetch of e+1 hides L2 latency.
// Budget ~228 VGPR (bfrag 64 + M 64 + D 32 + A-dbuf 32 + zc 16) -> (256,2).

typedef short short8 __attribute__((ext_vector_type(8)));
typedef __bf16 bf16x8 __attribute__((ext_vector_type(8)));
typedef float floatx16 __attribute__((ext_vector_type(16)));

#define NELEM 32
#define DIM   64
#define NSEG  1024
#define BROW  36   /* buf row stride (floats): 32 cols + 4 pad; 144B rows, 16B-aligned */

__device__ __forceinline__ unsigned short f32_to_bf16_rne(float f) {
  union { float f; unsigned int u; } v; v.f = f;
  unsigned int r = v.u + 0x7fffu + ((v.u >> 16) & 1u);
  return (unsigned short)(r >> 16);
}

// Block 0: exclusive scan of segment lengths -> offs[0..NSEG].
// Blocks 1..128: proxy fp32 -> fragment-major bf16 pa2.
//   task f = g*128 + e*4 + kk  (g = p>>5): frag at pa2 + f*512 shorts,
//   lane slot = +lane*8; element source: proxy[g*32 + (lane&31)][e][kk*16 + (lane>>5)*8 ..+8]
__global__ void sc_prep(const float* __restrict__ proxy,
                        const int* __restrict__ index,
                        short* __restrict__ pa2,
                        int* __restrict__ offs) {
  const int bx = blockIdx.x, t = threadIdx.x;
  if (bx == 0) {
    __shared__ int lsum[256];
    const int base = t * 4;
    const int i0 = index[base + 0], i1 = index[base + 1];
    const int i2 = index[base + 2], i3 = index[base + 3];
    const int s = i0 + i1 + i2 + i3;
    lsum[t] = s;
    __syncthreads();
    for (int off = 1; off < 256; off <<= 1) {
      int v = (t >= off) ? lsum[t - off] : 0;
      __syncthreads();
      lsum[t] += v;
      __syncthreads();
    }
    const int ex = lsum[t] - s;
    offs[base + 0] = ex;
    offs[base + 1] = ex + i0;
    offs[base + 2] = ex + i0 + i1;
    offs[base + 3] = ex + i0 + i1 + i2;
    if (t == 255) offs[NSEG] = ex + s;
  } else {
    const int wv = t >> 6, lane = t & 63;
    const int f = (bx - 1) * 4 + wv;         // 0..511
    const int g = f >> 7, e = (f >> 2) & 31, kk = f & 3;
    const int l31 = lane & 31, h = lane >> 5;
    const float* src = proxy + ((size_t)(g * 32 + l31) * NELEM + e) * DIM + kk * 16 + h * 8;
    float4 f0 = *(const float4*)(src);
    float4 f1 = *(const float4*)(src + 4);
    short8 fr;
    fr[0] = (short)f32_to_bf16_rne(f0.x);
    fr[1] = (short)f32_to_bf16_rne(f0.y);
    fr[2] = (short)f32_to_bf16_rne(f0.z);
    fr[3] = (short)f32_to_bf16_rne(f0.w);
    fr[4] = (short)f32_to_bf16_rne(f1.x);
    fr[5] = (short)f32_to_bf16_rne(f1.y);
    fr[6] = (short)f32_to_bf16_rne(f1.z);
    fr[7] = (short)f32_to_bf16_rne(f1.w);
    *(short8*)(pa2 + ((size_t)f * 64 + lane) * 8) = fr;  // coalesced 1KB/wave
  }
}

__global__ __launch_bounds__(256, 2) void sc_main(
    const float* __restrict__ x,
    const short* __restrict__ pa2,
    const int* __restrict__ offs,
    float* __restrict__ out,
    int nrows) {
  __shared__ float buf[128 * BROW];  // [p][col]: per-column partial sums
  __shared__ float red[4];

  const int b = blockIdx.x;
  const int tid = threadIdx.x;
  const int lane = tid & 63;
  const int g = tid >> 6;   // p-group: rows p = g*32 + 0..31
  const int l31 = lane & 31;
  const int h = lane >> 5;

  const int start = offs[b];
  const int end = offs[b + 1];
  const int len = end - start;
  const int first = start >> 5;
  const int ntiles = (len > 0) ? (((end + 31) >> 5) - first) : 0;
  const int npass = (ntiles + 3) >> 2;

  if (ntiles == 0) {
    for (int j = tid; j < 128 * BROW; j += 256) buf[j] = 0.f;
  }

  floatx16 zc;  // permanently-zero C operand (no per-chain acc init)
#pragma unroll
  for (int r = 0; r < 16; ++r) zc[r] = 0.f;

  // frag(g,e,kk) at pa2 + (g*128 + e*4 + kk)*512 + lane*8 shorts
  const short* abase = pa2 + (size_t)g * (128 * 512) + lane * 8;

  for (int pass = 0; pass < npass; ++pass) {
    // B-frags: the block's 4 n-tiles (shared work, each wave builds its own copy).
    // Invalid columns ZEROED -> D=0 for every e -> max contributes 0.
    short8 bfrag[4][4];
#pragma unroll
    for (int t4 = 0; t4 < 4; ++t4) {
      const int n = (first + pass * 4 + t4) * 32 + l31;
      const bool valid = (n >= start) && (n < end) && (n < nrows);
      const float* xr = x + (size_t)(valid ? n : 0) * DIM + h * 8;
#pragma unroll
      for (int kk = 0; kk < 4; ++kk) {
        float4 f0 = make_float4(0.f, 0.f, 0.f, 0.f), f1 = f0;
        if (valid) {
          f0 = *(const float4*)(xr + kk * 16);
          f1 = *(const float4*)(xr + kk * 16 + 4);
        }
        short8 fr;
        fr[0] = (short)f32_to_bf16_rne(f0.x);
        fr[1] = (short)f32_to_bf16_rne(f0.y);
        fr[2] = (short)f32_to_bf16_rne(f0.z);
        fr[3] = (short)f32_to_bf16_rne(f0.w);
        fr[4] = (short)f32_to_bf16_rne(f1.x);
        fr[5] = (short)f32_to_bf16_rne(f1.y);
        fr[6] = (short)f32_to_bf16_rne(f1.z);
        fr[7] = (short)f32_to_bf16_rne(f1.w);
        bfrag[t4][kk] = fr;
      }
    }

    // Running max over e, per tile, in MFMA C-layout registers.
    floatx16 M0, M1, M2, M3;
#pragma unroll
    for (int r = 0; r < 16; ++r) {
      M0[r] = -3.0e38f; M1[r] = -3.0e38f; M2[r] = -3.0e38f; M3[r] = -3.0e38f;
    }

    auto estep = [&](const short8 (&cur)[4], short8 (&nxt)[4], int enext, bool pf) {
      if (pf) {  // coalesced A prefetch for e+1 (4KB, covers L2 latency)
        const short* ap = abase + (size_t)enext * 2048;
#pragma unroll
        for (int kk = 0; kk < 4; ++kk)
          nxt[kk] = *(const short8*)(ap + kk * 512);
      }
      // pair 0: tiles 0,1
      {
        floatx16 d0, d1;
#pragma unroll
        for (int kk = 0; kk < 4; ++kk) {
          bf16x8 a = __builtin_bit_cast(bf16x8, cur[kk]);
          bf16x8 b0 = __builtin_bit_cast(bf16x8, bfrag[0][kk]);
          bf16x8 b1 = __builtin_bit_cast(bf16x8, bfrag[1][kk]);
          if (kk == 0) {
            d0 = __builtin_amdgcn_mfma_f32_32x32x16_bf16(a, b0, zc, 0, 0, 0);
            d1 = __builtin_amdgcn_mfma_f32_32x32x16_bf16(a, b1, zc, 0, 0, 0);
          } else {
            d0 = __builtin_amdgcn_mfma_f32_32x32x16_bf16(a, b0, d0, 0, 0, 0);
            d1 = __builtin_amdgcn_mfma_f32_32x32x16_bf16(a, b1, d1, 0, 0, 0);
          }
        }
#pragma unroll
        for (int r = 0; r < 16; ++r) {
          M0[r] = fmaxf(M0[r], d0[r]);
          M1[r] = fmaxf(M1[r], d1[r]);
        }
      }
      // pair 1: tiles 2,3
      {
        floatx16 d0, d1;
#pragma unroll
        for (int kk = 0; kk < 4; ++kk) {
          bf16x8 a = __builtin_bit_cast(bf16x8, cur[kk]);
          bf16x8 b2 = __builtin_bit_cast(bf16x8, bfrag[2][kk]);
          bf16x8 b3 = __builtin_bit_cast(bf16x8, bfrag[3][kk]);
          if (kk == 0) {
            d0 = __builtin_amdgcn_mfma_f32_32x32x16_bf16(a, b2, zc, 0, 0, 0);
            d1 = __builtin_amdgcn_mfma_f32_32x32x16_bf16(a, b3, zc, 0, 0, 0);
          } else {
            d0 = __builtin_amdgcn_mfma_f32_32x32x16_bf16(a, b2, d0, 0, 0, 0);
            d1 = __builtin_amdgcn_mfma_f32_32x32x16_bf16(a, b3, d1, 0, 0, 0);
          }
        }
#pragma unroll
        for (int r = 0; r < 16; ++r) {
          M2[r] = fmaxf(M2[r], d0[r]);
          M3[r] = fmaxf(M3[r], d1[r]);
        }
      }
    };

    short8 aA[4], aB[4];
#pragma unroll
    for (int kk = 0; kk < 4; ++kk)
      aA[kk] = *(const short8*)(abase + kk * 512);
    for (int e = 0; e < 32; e += 2) {  // unroll-2: compile-time dbuf index
      estep(aA, aB, e + 1, true);
      estep(aB, aA, e + 2, e < 30);
    }

    // Per-pass epilogue: tile-sum in C-layout, then 16 LDS writes per lane.
    // row r -> p = g*32 + (r&3) + 8*(r>>2) + 4*h ; col = l31.  (2-way = free)
#pragma unroll
    for (int r = 0; r < 16; ++r) {
      const float s = (M0[r] + M1[r]) + (M2[r] + M3[r]);
      const int p = g * 32 + (r & 3) + 8 * (r >> 2) + 4 * h;
      const int idx = p * BROW + l31;
      const float prev = (pass == 0) ? 0.f : buf[idx];
      buf[idx] = prev + s;
    }
  }
  __syncthreads();

  // Batched 32-col reduction + fused L2-normalize. 2 threads per p.
  const int p2 = tid >> 1, part = tid & 1;
  const float* bp = buf + p2 * BROW + part * 16;
  float4 v0 = *(const float4*)(bp + 0);
  float4 v1 = *(const float4*)(bp + 4);
  float4 v2 = *(const float4*)(bp + 8);
  float4 v3 = *(const float4*)(bp + 12);
  float s16 = ((v0.x + v0.y) + (v0.z + v0.w)) + ((v1.x + v1.y) + (v1.z + v1.w)) +
              ((v2.x + v2.y) + (v2.z + v2.w)) + ((v3.x + v3.y) + (v3.z + v3.w));
  const float s32 = s16 + __shfl_xor(s16, 1, 64);  // pooled[b][p2]

  float sq = part ? 0.f : s32 * s32;
#pragma unroll
  for (int off = 1; off <= 32; off <<= 1) sq += __shfl_xor(sq, off, 64);
  if (lane == 0) red[tid >> 6] = sq;
  __syncthreads();
  const float ss = (red[0] + red[1]) + (red[2] + red[3]);
  const float inv = 1.f / fmaxf(sqrtf(ss), 1e-12f);
  if (part == 0) out[(b << 7) + p2] = s32 * inv;
}

extern "C" void kernel_launch(void* const* d_in, const int* in_sizes, int n_in,
                              void* d_out, int out_size, void* d_ws, size_t ws_size,
                              hipStream_t stream) {
  (void)n_in; (void)out_size; (void)ws_size;
  const float* x = (const float*)d_in[0];      // [N, 64] fp32
  const float* proxy = (const float*)d_in[1];  // [128, 32, 64] fp32
  const int* index = (const int*)d_in[2];      // [1024] int32
  float* out = (float*)d_out;                  // [1024, 128] fp32
  const int nrows = in_sizes[0] / DIM;

  int* offs = (int*)d_ws;                      // (NSEG+1) ints
  short* pa2 = (short*)((char*)d_ws + 8192);   // 512 KB fragment-major bf16 proxy

  sc_prep<<<129, 256, 0, stream>>>(proxy, index, pa2, offs);
  sc_main<<<NSEG, 256, 0, stream>>>(x, pa2, offs, out, nrows);
}